// Round 1
// 349.778 us; speedup vs baseline: 1.0658x; 1.0658x over previous
//
#include <hip/hip_runtime.h>
#include <hip/hip_bf16.h>
#include <stdint.h>

typedef _Float16 f16;
typedef __attribute__((ext_vector_type(8))) _Float16 f16x8;
typedef __attribute__((ext_vector_type(4))) _Float16 f16x4;
typedef __attribute__((ext_vector_type(4))) float f32x4;

__device__ __forceinline__ void g2l16(const void* g, void* l) {
  __builtin_amdgcn_global_load_lds(
      (const __attribute__((address_space(1))) uint32_t*)g,
      (__attribute__((address_space(3))) uint32_t*)l, 16, 0, 0);
}

// ---------------- fused weight transpose + fp32->f16 convert (all 6 weights) ----------------
__global__ __launch_bounds__(256)
void wconv_all_kernel(const float* __restrict__ Wq, const float* __restrict__ Wk,
                      const float* __restrict__ Wv, const float* __restrict__ Wp,
                      const float* __restrict__ Wfc, const float* __restrict__ Wmp,
                      f16* __restrict__ Dq, f16* __restrict__ Dk, f16* __restrict__ Dv,
                      f16* __restrict__ Dp, f16* __restrict__ Dfc, f16* __restrict__ Dmp)
{
  __shared__ float tile[32][33];
  int id = blockIdx.x;
  const float* W; f16* Wt; int K, N, local;
  if      (id < 1024) { W = Wq;  Wt = Dq;  K = 1024; N = 1024; local = id; }
  else if (id < 2048) { W = Wk;  Wt = Dk;  K = 1024; N = 1024; local = id - 1024; }
  else if (id < 3072) { W = Wv;  Wt = Dv;  K = 1024; N = 1024; local = id - 2048; }
  else if (id < 4096) { W = Wp;  Wt = Dp;  K = 1024; N = 1024; local = id - 3072; }
  else if (id < 8192) { W = Wfc; Wt = Dfc; K = 1024; N = 4096; local = id - 4096; }
  else                { W = Wmp; Wt = Dmp; K = 4096; N = 1024; local = id - 8192; }
  int ntx = N >> 5;
  int n0 = (local % ntx) * 32, k0 = (local / ntx) * 32;
  int tx = threadIdx.x & 31, ty = threadIdx.x >> 5;
#pragma unroll
  for (int i = 0; i < 4; ++i)
    tile[ty + 8*i][tx] = W[(size_t)(k0 + ty + 8*i) * N + (n0 + tx)];
  __syncthreads();
#pragma unroll
  for (int i = 0; i < 4; ++i)
    Wt[(size_t)(n0 + ty + 8*i) * K + (k0 + tx)] = (f16)tile[tx][ty + 8*i];
}

// ---------------- scaled = x*lr + x0*lx ; pre = rmsnorm(scaled) ----------------
__global__ __launch_bounds__(256)
void scale_rms_kernel(const float* __restrict__ x, const float* __restrict__ x0,
                      const float* __restrict__ lamR, const float* __restrict__ lamX,
                      float* __restrict__ scaled, f16* __restrict__ pre)
{
  const int C = 1024;
  int row = blockIdx.x, tid = threadIdx.x;
  float lr = lamR[0], lx = lamX[0];
  size_t base = (size_t)row * C;
  float4 xv = ((const float4*)(x + base))[tid];
  float4 zv = ((const float4*)(x0 + base))[tid];
  float4 sv;
  sv.x = xv.x*lr + zv.x*lx;  sv.y = xv.y*lr + zv.y*lx;
  sv.z = xv.z*lr + zv.z*lx;  sv.w = xv.w*lr + zv.w*lx;
  float ss = sv.x*sv.x + sv.y*sv.y + sv.z*sv.z + sv.w*sv.w;
#pragma unroll
  for (int off = 32; off >= 1; off >>= 1) ss += __shfl_xor(ss, off);
  __shared__ float red[4];
  if ((tid & 63) == 0) red[tid >> 6] = ss;
  __syncthreads();
  float tot = red[0] + red[1] + red[2] + red[3];
  float rs = rsqrtf(tot * (1.0f / 1024.0f) + 1e-5f);
  ((float4*)(scaled + base))[tid] = sv;
  f16* p = pre + base + tid * 4;
  p[0] = (f16)(sv.x * rs); p[1] = (f16)(sv.y * rs);
  p[2] = (f16)(sv.z * rs); p[3] = (f16)(sv.w * rs);
}

// ---------------- combine_rms: scaled2 = resid+p0+p1 (f16 partials) ; pre2 = rms ----------------
__global__ __launch_bounds__(256)
void combine_rms_kernel(const float* __restrict__ resid, const f16* __restrict__ p0,
                        const f16* __restrict__ p1, float* __restrict__ scaled2,
                        f16* __restrict__ pre2)
{
  const int C = 1024;
  int row = blockIdx.x, tid = threadIdx.x;
  size_t base = (size_t)row * C;
  float4 rv = ((const float4*)(resid + base))[tid];
  f16x4 av = ((const f16x4*)(p0 + base))[tid];
  f16x4 bv = ((const f16x4*)(p1 + base))[tid];
  float4 sv;
  sv.x = rv.x + (float)av[0] + (float)bv[0];
  sv.y = rv.y + (float)av[1] + (float)bv[1];
  sv.z = rv.z + (float)av[2] + (float)bv[2];
  sv.w = rv.w + (float)av[3] + (float)bv[3];
  float ss = sv.x*sv.x + sv.y*sv.y + sv.z*sv.z + sv.w*sv.w;
#pragma unroll
  for (int off = 32; off >= 1; off >>= 1) ss += __shfl_xor(ss, off);
  __shared__ float red[4];
  if ((tid & 63) == 0) red[tid >> 6] = ss;
  __syncthreads();
  float tot = red[0] + red[1] + red[2] + red[3];
  float rs = rsqrtf(tot * (1.0f / 1024.0f) + 1e-5f);
  ((float4*)(scaled2 + base))[tid] = sv;
  f16* p = pre2 + base + tid * 4;
  p[0] = (f16)(sv.x * rs); p[1] = (f16)(sv.y * rs);
  p[2] = (f16)(sv.z * rs); p[3] = (f16)(sv.w * rs);
}

// ---------------- combine_out: out = resid + sum of 4 f16 partials ----------------
__global__ __launch_bounds__(256)
void combine_out4_kernel(const float* __restrict__ resid, const f16* __restrict__ parts,
                         size_t pstride, float* __restrict__ out)
{
  size_t i = (size_t)blockIdx.x * 256 + threadIdx.x;
  float4 rv = ((const float4*)resid)[i];
  float4 sv = rv;
#pragma unroll
  for (int z = 0; z < 4; ++z) {
    f16x4 av = ((const f16x4*)(parts + z * pstride))[i];
    sv.x += (float)av[0]; sv.y += (float)av[1];
    sv.z += (float)av[2]; sv.w += (float)av[3];
  }
  ((float4*)out)[i] = sv;
}

// ---------------- fused RoPE + rmsnorm on q and k, (B*T, H, 64) f16 ----------------
__global__ __launch_bounds__(256)
void rope_rms_kernel(f16* __restrict__ Xq, f16* __restrict__ Xk,
                     const float* __restrict__ cs, const float* __restrict__ sn)
{
  const int MH = 4096 * 16;
  int ridx = blockIdx.x * 4 + (threadIdx.x >> 6);  // over 2*B*T*H
  f16* X = (ridx < MH) ? Xq : Xk;
  if (ridx >= MH) ridx -= MH;
  int lane = threadIdx.x & 63;
  int h = ridx & 15;
  int bt = ridx >> 4;
  int t = bt & 2047;
  size_t base = (size_t)bt * 1024 + h * 64;
  float xv = (float)X[base + lane];
  float other = __shfl_xor(xv, 32);
  float rot = (lane < 32) ? -other : other;
  float c = cs[t * 64 + lane], s = sn[t * 64 + lane];
  float y = xv * c + rot * s;
  float ss = y * y;
#pragma unroll
  for (int off = 32; off >= 1; off >>= 1) ss += __shfl_xor(ss, off);
  float r = rsqrtf(ss * (1.0f / 64.0f) + 1e-5f);
  X[base + lane] = (f16)(y * r);
}

// ---------------- legacy 128x128 GEMM (kept for proj, small N) ----------------
template<int EPI>
__global__ __launch_bounds__(256)
void gemm_kernel(const f16* __restrict__ A, const f16* __restrict__ Bt,
                 void* __restrict__ out, int M, int N, int K, int nb, int zb)
{
  __shared__ __align__(16) f16 smem[4 * 128 * 32];   // As0|As1|Bs0|Bs1
  const int tid = threadIdx.x;
  const int wave = tid >> 6, lane = tid & 63;
  const int col = lane & 15, quad = lane >> 4;
  const int id = blockIdx.x;
  const int xcd = id & 7, s = id >> 3;
  const int n_i = s % nb;
  const int p = s / nb;
  const int mpx = (M >> 7) >> 3;
  const int zz = p / mpx;
  const int m_i = xcd * mpx + (p % mpx);
  const int m0 = m_i * 128, n0 = n_i * 128;
  const int wm = (wave >> 1) * 64, wn = (wave & 1) * 64;
  const int Ksub = K / zb;
  const int kBeg = zz * Ksub;
  const int nIter = Ksub >> 5;
  f32x4 acc[4][4] = {};

  const size_t rowb = (size_t)K * 2;
  const char* Agp = (const char*)A  + (size_t)m0 * rowb;
  const char* Bgp = (const char*)Bt + (size_t)n0 * rowb;

  const int r_st = (tid >> 2);
  const int cb_st = (tid & 3) << 4;
  const int lb0 = (wave * 64) << 4;
  const int lb1 = (256 + wave * 64) << 4;

#define STAGE(buf, k0)                                                           \
  {                                                                              \
    const size_t koff = (size_t)(k0) * 2;                                        \
    g2l16(Agp + (size_t)r_st * rowb + koff + cb_st,                              \
          (char*)smem + (buf) * 8192 + lb0);                                     \
    g2l16(Agp + (size_t)(r_st + 64) * rowb + koff + cb_st,                       \
          (char*)smem + (buf) * 8192 + lb1);                                     \
    g2l16(Bgp + (size_t)r_st * rowb + koff + cb_st,                              \
          (char*)smem + 16384 + (buf) * 8192 + lb0);                             \
    g2l16(Bgp + (size_t)(r_st + 64) * rowb + koff + cb_st,                       \
          (char*)smem + 16384 + (buf) * 8192 + lb1);                             \
  }

  STAGE(0, kBeg)
  for (int kt = 0; kt < nIter; ++kt) {
    __syncthreads();
    if (kt + 1 < nIter) STAGE((kt + 1) & 1, kBeg + (kt + 1) * 32)
    const f16* As = smem + (kt & 1) * 4096;
    const f16* Bs = smem + 8192 + (kt & 1) * 4096;
    f16x8 af[4], bf[4];
#pragma unroll
    for (int t = 0; t < 4; ++t)
      af[t] = *(const f16x8*)(As + (wm + t*16 + col) * 32 + quad * 8);
#pragma unroll
    for (int t = 0; t < 4; ++t)
      bf[t] = *(const f16x8*)(Bs + (wn + t*16 + col) * 32 + quad * 8);
#pragma unroll
    for (int mt = 0; mt < 4; ++mt)
#pragma unroll
      for (int nt = 0; nt < 4; ++nt)
        acc[mt][nt] = __builtin_amdgcn_mfma_f32_16x16x32_f16(af[mt], bf[nt], acc[mt][nt], 0, 0, 0);
  }
#undef STAGE
  f16* ep = smem + wave * 1024;
  f16* outz = (EPI == 4) ? ((f16*)out + (size_t)zz * M * N) : (f16*)out;
#pragma unroll
  for (int mt = 0; mt < 4; ++mt) {
#pragma unroll
    for (int nt = 0; nt < 4; ++nt) {
#pragma unroll
      for (int r = 0; r < 4; ++r) {
        float v = acc[mt][nt][r];
        if (EPI == 1) { float tv = v > 0.0f ? v : 0.0f; v = tv * tv; }
        ep[(quad * 4 + r) * 64 + ((nt ^ quad) * 16 + col)] = (f16)v;
      }
    }
#pragma unroll
    for (int j = 0; j < 2; ++j) {
      int e = j * 64 + lane;
      int row = e >> 3, rb = e & 7;
      int phys16 = (((rb >> 1) ^ (row >> 2)) << 1) + (rb & 1);
      f16x8 vv = *(const f16x8*)(ep + row * 64 + phys16 * 8);
      int grow = m0 + wm + mt * 16 + row;
      int gcol = n0 + wn + rb * 8;
      *(f16x8*)(outz + (size_t)grow * N + gcol) = vv;
    }
  }
}

// ======================= 256x256 8-wave counted-vmcnt GEMM =======================
// BM=BN=256, BK=64, 512 thr (8 waves, 2Mx4N), LDS 128KB (2 bufs x (A32K|B32K)).
// Schedule per K-tile t:  vmcnt(8) ; barrier ; ds_read+MFMA (buf t&1) ;
//                         lgkmcnt(0) ; barrier ; STAGE(t+2 -> buf t&1).
// Stage of tile t+2 is issued only after ALL waves drained reads of tile t
// (same buffer) -> race-free; gate vmcnt(8) leaves tile t+1's 8 loads in
// flight -> never drains to 0 in steady state (T4).
// LDS layout: rows of 64 f16 (128B), 16B slots XOR-swizzled by (row&7).
// Swizzle applied on BOTH the global source addr (stage) and ds_read addr.

__device__ __forceinline__ void stage256(const char* Agp, const char* Bgp, size_t rowb,
                                         char* lds, int st_r, size_t koff, int tid)
{
#pragma unroll
  for (int j = 0; j < 4; ++j) {
    g2l16(Agp + (size_t)(st_r + j * 64) * rowb + koff, lds + j * 8192 + tid * 16);
    g2l16(Bgp + (size_t)(st_r + j * 64) * rowb + koff, lds + 32768 + j * 8192 + tid * 16);
  }
}

template<int EPI>
__global__ __launch_bounds__(512, 2)
void gemm256_kernel(const f16* __restrict__ A, const f16* __restrict__ Bt,
                    void* __restrict__ out, int M, int N, int K, int nb, int zb)
{
  __shared__ __align__(16) f16 smem[65536];   // 128 KB
  const int tid = threadIdx.x;
  const int wave = tid >> 6, lane = tid & 63;
  const int col = lane & 15, quad = lane >> 4;
  const int id = blockIdx.x;
  const int xcd = id & 7, sb = id >> 3;
  const int n_i = sb % nb;
  const int p = sb / nb;
  const int mpx = (M >> 8) >> 3;
  const int zz = p / mpx;
  const int m_i = xcd * mpx + (p % mpx);
  const int m0 = m_i * 256, n0 = n_i * 256;
  const int wm = (wave >> 2) * 128, wn = (wave & 3) * 64;
  const int Ksub = K / zb;
  const int kBeg = zz * Ksub;
  const int ntiles = Ksub >> 6;               // always even here (16)
  f32x4 acc[8][4] = {};

  const size_t rowb = (size_t)K * 2;
  const char* Agp = (const char*)A  + (size_t)m0 * rowb;
  const char* Bgp = (const char*)Bt + (size_t)n0 * rowb;

  const int st_r = tid >> 3;                                   // 0..63 row-in-64-stripe
  const size_t st_so = (size_t)(((tid & 7) ^ ((tid >> 3) & 7)) << 4);  // swizzled src slot

  stage256(Agp, Bgp, rowb, (char*)smem,         st_r, (size_t)kBeg * 2 + st_so, tid);
  stage256(Agp, Bgp, rowb, (char*)smem + 65536, st_r, (size_t)(kBeg + 64) * 2 + st_so, tid);

  for (int t = 0; t < ntiles; ++t) {
    if (t < ntiles - 1) asm volatile("s_waitcnt vmcnt(8)" ::: "memory");
    else                asm volatile("s_waitcnt vmcnt(0)" ::: "memory");
    __builtin_amdgcn_s_barrier();
    asm volatile("" ::: "memory");

    const f16* As = smem + (t & 1) * 32768;
    const f16* Bs = As + 16384;
    f16x8 bf[4][2];
#pragma unroll
    for (int ct = 0; ct < 4; ++ct)
#pragma unroll
      for (int ks = 0; ks < 2; ++ks)
        bf[ct][ks] = *(const f16x8*)(Bs + (wn + ct*16 + col) * 64 +
                                     (((ks*4 + quad) ^ (col & 7)) << 3));
#pragma unroll
    for (int sp = 0; sp < 4; ++sp) {
      f16x8 af[2][2];
#pragma unroll
      for (int i = 0; i < 2; ++i)
#pragma unroll
        for (int ks = 0; ks < 2; ++ks)
          af[i][ks] = *(const f16x8*)(As + (wm + (sp*2 + i)*16 + col) * 64 +
                                      (((ks*4 + quad) ^ (col & 7)) << 3));
      __builtin_amdgcn_s_setprio(1);
#pragma unroll
      for (int i = 0; i < 2; ++i)
#pragma unroll
        for (int ct = 0; ct < 4; ++ct)
#pragma unroll
          for (int ks = 0; ks < 2; ++ks)
            acc[sp*2 + i][ct] = __builtin_amdgcn_mfma_f32_16x16x32_f16(
                af[i][ks], bf[ct][ks], acc[sp*2 + i][ct], 0, 0, 0);
      __builtin_amdgcn_s_setprio(0);
    }

    asm volatile("s_waitcnt lgkmcnt(0)" ::: "memory");
    __builtin_amdgcn_s_barrier();
    asm volatile("" ::: "memory");
    if (t + 2 < ntiles)
      stage256(Agp, Bgp, rowb, (char*)smem + (t & 1) * 65536, st_r,
               (size_t)(kBeg + (t + 2) * 64) * 2 + st_so, tid);
  }

  // epilogue: all LDS free (loop ended with barrier); per-wave 16x64 slab
  f16* ep = smem + wave * 1024;
  f16* outz = (EPI == 4) ? ((f16*)out + (size_t)zz * M * N) : (f16*)out;
#pragma unroll
  for (int mt = 0; mt < 8; ++mt) {
#pragma unroll
    for (int ct = 0; ct < 4; ++ct) {
#pragma unroll
      for (int r = 0; r < 4; ++r) {
        float v = acc[mt][ct][r];
        if (EPI == 1) { float tv = v > 0.0f ? v : 0.0f; v = tv * tv; }
        ep[(quad * 4 + r) * 64 + ((ct ^ quad) * 16 + col)] = (f16)v;
      }
    }
#pragma unroll
    for (int j = 0; j < 2; ++j) {
      int e = j * 64 + lane;
      int row = e >> 3, rb = e & 7;
      int phys16 = (((rb >> 1) ^ (row >> 2)) << 1) + (rb & 1);
      f16x8 vv = *(const f16x8*)(ep + row * 64 + phys16 * 8);
      int grow = m0 + wm + mt * 16 + row;
      int gcol = n0 + wn + rb * 8;
      *(f16x8*)(outz + (size_t)grow * N + gcol) = vv;
    }
  }
}

// ---------------- fused QKV GEMM on the 256x256 structure ----------------
// A[4096,1024] @ Wqkv[3072,1024]^T. N-blocks 0..3 -> Q, 4..7 -> K, 8..11 -> V.
__global__ __launch_bounds__(512, 2)
void gemm256_qkv_kernel(const f16* __restrict__ A, const f16* __restrict__ Bt,
                        f16* __restrict__ qb, f16* __restrict__ kbuf, f16* __restrict__ vtg)
{
  const int K = 1024, nb = 12, ntiles = 16;
  __shared__ __align__(16) f16 smem[65536];
  const int tid = threadIdx.x;
  const int wave = tid >> 6, lane = tid & 63;
  const int col = lane & 15, quad = lane >> 4;
  const int id = blockIdx.x;
  const int xcd = id & 7, sb = id >> 3;
  const int n_i = sb % nb;
  const int m_i = xcd * 2 + (sb / nb);
  const int m0 = m_i * 256, n0 = n_i * 256;
  const int wm = (wave >> 2) * 128, wn = (wave & 3) * 64;
  f32x4 acc[8][4] = {};

  const size_t rowb = (size_t)K * 2;
  const char* Agp = (const char*)A  + (size_t)m0 * rowb;
  const char* Bgp = (const char*)Bt + (size_t)n0 * rowb;

  const int st_r = tid >> 3;
  const size_t st_so = (size_t)(((tid & 7) ^ ((tid >> 3) & 7)) << 4);

  stage256(Agp, Bgp, rowb, (char*)smem,         st_r, st_so, tid);
  stage256(Agp, Bgp, rowb, (char*)smem + 65536, st_r, (size_t)64 * 2 + st_so, tid);

  for (int t = 0; t < ntiles; ++t) {
    if (t < ntiles - 1) asm volatile("s_waitcnt vmcnt(8)" ::: "memory");
    else                asm volatile("s_waitcnt vmcnt(0)" ::: "memory");
    __builtin_amdgcn_s_barrier();
    asm volatile("" ::: "memory");

    const f16* As = smem + (t & 1) * 32768;
    const f16* Bs = As + 16384;
    f16x8 bf[4][2];
#pragma unroll
    for (int ct = 0; ct < 4; ++ct)
#pragma unroll
      for (int ks = 0; ks < 2; ++ks)
        bf[ct][ks] = *(const f16x8*)(Bs + (wn + ct*16 + col) * 64 +
                                     (((ks*4 + quad) ^ (col & 7)) << 3));
#pragma unroll
    for (int sp = 0; sp < 4; ++sp) {
      f16x8 af[2][2];
#pragma unroll
      for (int i = 0; i < 2; ++i)
#pragma unroll
        for (int ks = 0; ks < 2; ++ks)
          af[i][ks] = *(const f16x8*)(As + (wm + (sp*2 + i)*16 + col) * 64 +
                                      (((ks*4 + quad) ^ (col & 7)) << 3));
      __builtin_amdgcn_s_setprio(1);
#pragma unroll
      for (int i = 0; i < 2; ++i)
#pragma unroll
        for (int ct = 0; ct < 4; ++ct)
#pragma unroll
          for (int ks = 0; ks < 2; ++ks)
            acc[sp*2 + i][ct] = __builtin_amdgcn_mfma_f32_16x16x32_f16(
                af[i][ks], bf[ct][ks], acc[sp*2 + i][ct], 0, 0, 0);
      __builtin_amdgcn_s_setprio(0);
    }

    asm volatile("s_waitcnt lgkmcnt(0)" ::: "memory");
    __builtin_amdgcn_s_barrier();
    asm volatile("" ::: "memory");
    if (t + 2 < ntiles)
      stage256(Agp, Bgp, rowb, (char*)smem + (t & 1) * 65536, st_r,
               (size_t)((t + 2) * 64) * 2 + st_so, tid);
  }

  const int cw = n0 + wn;          // wave's 64-col base in 0..3071
  const int sel = cw >> 10;        // 0: Q, 1: K, 2: V (wave-uniform)
  if (sel < 2) {
    f16* dst = (sel == 0) ? qb : kbuf;
    const int cbase = cw & 1023;
    f16* ep = smem + wave * 1024;
#pragma unroll
    for (int mt = 0; mt < 8; ++mt) {
#pragma unroll
      for (int ct = 0; ct < 4; ++ct)
#pragma unroll
        for (int r = 0; r < 4; ++r)
          ep[(quad * 4 + r) * 64 + ((ct ^ quad) * 16 + col)] = (f16)acc[mt][ct][r];
#pragma unroll
      for (int j = 0; j < 2; ++j) {
        int e = j * 64 + lane;
        int row = e >> 3, rb = e & 7;
        int phys16 = (((rb >> 1) ^ (row >> 2)) << 1) + (rb & 1);
        f16x8 vv = *(const f16x8*)(ep + row * 64 + phys16 * 8);
        int grow = m0 + wm + mt * 16 + row;
        *(f16x8*)(dst + (size_t)grow * 1024 + cbase + rb * 8) = vv;
      }
    }
  } else {
    // V: acc[mt][ct][0..3] are 4 consecutive t (rows), same output d -> direct 8B store
#pragma unroll
    for (int mt = 0; mt < 8; ++mt) {
      int t0 = m0 + wm + mt * 16 + quad * 4;
      int b = t0 >> 11, t = t0 & 2047;
#pragma unroll
      for (int ct = 0; ct < 4; ++ct) {
        int dd = (cw & 1023) + ct * 16 + col;   // 0..1023 -> h = dd>>6, d = dd&63
        int hh = dd >> 6, d = dd & 63;
        f16x4 vv;
#pragma unroll
        for (int r = 0; r < 4; ++r) vv[r] = (f16)acc[mt][ct][r];
        *(f16x4*)(vtg + ((size_t)((b * 16 + hh) * 64 + d)) * 2048 + t) = vv;
      }
    }
  }
}

// ---------------- causal flash attention, hd=64, no-max softmax, dbuf staging ----------------
__global__ __launch_bounds__(256)
void attn_kernel(const f16* __restrict__ Q, const f16* __restrict__ Kc,
                 const f16* __restrict__ Vt, f16* __restrict__ O)
{
  const int T = 2048, C = 1024;
  __shared__ __align__(16) f16 Ks[2][64 * 64];
  __shared__ __align__(16) f16 Vs[2][64 * 64];
  __shared__ __align__(16) f16 Ps[4][16 * 64];
  const int tid = threadIdx.x, wave = tid >> 6, lane = tid & 63;
  const int col = lane & 15, quad = lane >> 4;
  const int bh = blockIdx.x, b = bh >> 4, h = bh & 15;
  const int qt = (int)gridDim.y - 1 - (int)blockIdx.y;
  const int q0 = qt * 64;

  const f16* qb = Q  + ((size_t)b * T) * C + h * 64;
  const f16* kb = Kc + ((size_t)b * T) * C + h * 64;
  const f16* vb = Vt + ((size_t)bh * 64) * T;

  f16x8 aq[2];
#pragma unroll
  for (int ks = 0; ks < 2; ++ks)
    aq[ks] = *(const f16x8*)(qb + (size_t)(q0 + wave*16 + col) * C + ks*32 + quad*8);

  f32x4 o_acc[4];
#pragma unroll
  for (int dt = 0; dt < 4; ++dt) o_acc[dt] = (f32x4){0.f,0.f,0.f,0.f};
  float l_part[4] = {0.f, 0.f, 0.f, 0.f};

  const int srow = lane >> 3;
  const int sblk = (lane & 7) ^ srow;

#pragma unroll
  for (int i = 0; i < 2; ++i) {
    int r0 = wave * 16 + 8 * i;
    g2l16(kb + (size_t)(r0 + srow) * C + sblk * 8, (char*)Ks[0] + r0 * 128);
    g2l16(vb + (size_t)(r0 + srow) * T + sblk * 8, (char*)Vs[0] + r0 * 128);
  }

  int cur = 0;
  for (int kt = 0; kt <= qt; ++kt) {
    __syncthreads();

    if (kt < qt) {
      const int ks1 = (kt + 1) * 64;
#pragma unroll
      for (int i = 0; i < 2; ++i) {
        int r0 = wave * 16 + 8 * i;
        g2l16(kb + (size_t)(ks1 + r0 + srow) * C + sblk * 8, (char*)Ks[cur ^ 1] + r0 * 128);
        g2l16(vb + (size_t)(r0 + srow) * T + ks1 + sblk * 8, (char*)Vs[cur ^ 1] + r0 * 128);
      }
    }

    f32x4 s[4];
#pragma unroll
    for (int nt = 0; nt < 4; ++nt) s[nt] = (f32x4){0.f,0.f,0.f,0.f};
#pragma unroll
    for (int ks = 0; ks < 2; ++ks) {
#pragma unroll
      for (int nt = 0; nt < 4; ++nt) {
        int key = nt * 16 + col;
        f16x8 bk = *(const f16x8*)(Ks[cur] + key * 64 + (((ks*4 + quad) ^ (key & 7)) * 8));
        s[nt] = __builtin_amdgcn_mfma_f32_16x16x32_f16(aq[ks], bk, s[nt], 0, 0, 0);
      }
    }

    const bool masked = (kt == qt);
#pragma unroll
    for (int r = 0; r < 4; ++r) {
      const int qloc = quad * 4 + r;
      float p[4];
#pragma unroll
      for (int nt = 0; nt < 4; ++nt) {
        float pv = __expf(s[nt][r] * 0.125f);
        if (masked && (nt * 16 + col > wave * 16 + qloc)) pv = 0.0f;
        p[nt] = pv;
      }
      l_part[r] += (p[0] + p[1]) + (p[2] + p[3]);
#pragma unroll
      for (int nt = 0; nt < 4; ++nt) {
        int kblk = nt * 2 + (col >> 3);
        Ps[wave][qloc * 64 + ((kblk ^ (qloc & 7)) * 8) + (col & 7)] = (f16)p[nt];
      }
    }

#pragma unroll
    for (int ks = 0; ks < 2; ++ks) {
      f16x8 ap = *(const f16x8*)(&Ps[wave][0] + col * 64 + (((ks*4 + quad) ^ (col & 7)) * 8));
#pragma unroll
      for (int dt = 0; dt < 4; ++dt) {
        int d = dt * 16 + col;
        f16x8 bv = *(const f16x8*)(Vs[cur] + d * 64 + (((ks*4 + quad) ^ (d & 7)) * 8));
        o_acc[dt] = __builtin_amdgcn_mfma_f32_16x16x32_f16(ap, bv, o_acc[dt], 0, 0, 0);
      }
    }
    cur ^= 1;
  }

#pragma unroll
  for (int r = 0; r < 4; ++r) {
#pragma unroll
    for (int off = 8; off >= 1; off >>= 1)
      l_part[r] += __shfl_xor(l_part[r], off, 16);
  }
#pragma unroll
  for (int dt = 0; dt < 4; ++dt) {
#pragma unroll
    for (int r = 0; r < 4; ++r) {
      int qr = q0 + wave * 16 + quad * 4 + r;
      float v = o_acc[dt][r] / l_part[r];
      O[((size_t)b * T + qr) * C + h * 64 + dt * 16 + col] = (f16)v;
    }
  }
}

// ---------------- orchestration ----------------
extern "C" void kernel_launch(void* const* d_in, const int* in_sizes, int n_in,
                              void* d_out, int out_size, void* d_ws, size_t ws_size,
                              hipStream_t stream)
{
  const float* x    = (const float*)d_in[0];
  const float* x0   = (const float*)d_in[1];
  const float* lamR = (const float*)d_in[2];
  const float* lamX = (const float*)d_in[3];
  const float* cs   = (const float*)d_in[4];
  const float* sn   = (const float*)d_in[5];
  const float* Wq   = (const float*)d_in[6];
  const float* Wk   = (const float*)d_in[7];
  const float* Wv   = (const float*)d_in[8];
  const float* Wp   = (const float*)d_in[9];
  const float* Wfc  = (const float*)d_in[10];
  const float* Wmp  = (const float*)d_in[11];
  float* out = (float*)d_out;

  const int B = 2, T = 2048, C = 1024, H = 16;
  const int M = B * T;  // 4096
  const size_t MB = 1ull << 20;
  char* ws = (char*)d_ws;
  f16*   Wqkv_t = (f16*)(ws + 0 * MB);     // 6 MB
  f16*   Wp_t   = (f16*)(ws + 6 * MB);     // 2 MB
  f16*   Wfc_t  = (f16*)(ws + 8 * MB);     // 8 MB
  f16*   Wmp_t  = (f16*)(ws + 16 * MB);    // 8 MB
  float* scaled  = (float*)(ws + 24 * MB); // 16 MB fp32 [later: mlp partials z0,z1]
  f16*   pre     = (f16*)(ws + 40 * MB);   // 8 MB       [later: attnOut -> mlp partial z2]
  f16*   qb      = (f16*)(ws + 48 * MB);   // 8 MB       [later: pre2 -> mlp partial z3]
  f16*   kbuf    = (f16*)(ws + 56 * MB);   // 8 MB
  f16*   vtg     = (f16*)(ws + 64 * MB);   // 8 MB V^T
  float* scaled2 = (float*)(ws + 72 * MB); // 16 MB fp32
  f16*   hbuf    = (f16*)(ws + 88 * MB);   // 32 MB      [first: proj f16 partials 2x8MB]
  f16*   attnOut = pre;
  f16*   pre2    = qb;
  f16*   projP   = (f16*)(ws + 88 * MB);   // 2 x 8 MB f16 (before hbuf written)
  f16*   mlpP    = (f16*)(ws + 24 * MB);   // 4 x 8 MB f16 (scaled/pre/qb all dead)

  dim3 tb(256);
  dim3 tb5(512);
  wconv_all_kernel<<<dim3(12288), tb, 0, stream>>>(
      Wq, Wk, Wv, Wp, Wfc, Wmp,
      Wqkv_t, Wqkv_t + 1024*1024, Wqkv_t + 2048*1024, Wp_t, Wfc_t, Wmp_t);

  scale_rms_kernel<<<M, tb, 0, stream>>>(x, x0, lamR, lamX, scaled, pre);

  // fused QKV GEMM: 256^2 tiles, 192 blocks, counted-vmcnt pipeline
  gemm256_qkv_kernel<<<dim3(192), tb5, 0, stream>>>(pre, Wqkv_t, qb, kbuf, vtg);

  rope_rms_kernel<<<(M * H) / 2, tb, 0, stream>>>(qb, kbuf, cs, sn);

  // grid (bh, qt): bh fastest -> per-head XCD pinning
  attn_kernel<<<dim3(B * H, T/64), tb, 0, stream>>>(qb, kbuf, vtg, attnOut);

  // proj GEMM split-K=2 (512 blocks, legacy 128^2) -> f16 partials ; combine + rms
  gemm_kernel<4><<<dim3(8 * 32 * 2), tb, 0, stream>>>(attnOut, Wp_t, projP, M, C, C, 8, 2);
  combine_rms_kernel<<<M, tb, 0, stream>>>(scaled, projP, projP + (size_t)M*C, scaled2, pre2);

  // fc GEMM + relu^2: 256^2 tiles, 256 blocks
  gemm256_kernel<1><<<dim3(256), tb5, 0, stream>>>(pre2, Wfc_t, hbuf, M, 4*C, C, 16, 1);

  // mlp proj split-K=4: 256^2 tiles, 256 blocks -> f16 partials ; combine into out
  gemm256_kernel<4><<<dim3(256), tb5, 0, stream>>>(hbuf, Wmp_t, mlpP, M, C, 4*C, 4, 4);
  combine_out4_kernel<<<(M*C)/1024, tb, 0, stream>>>(scaled2, mlpP, (size_t)M*C, out);
}

// Round 2
// 347.630 us; speedup vs baseline: 1.0724x; 1.0062x over previous
//
#include <hip/hip_runtime.h>
#include <hip/hip_bf16.h>
#include <stdint.h>

typedef _Float16 f16;
typedef __attribute__((ext_vector_type(8))) _Float16 f16x8;
typedef __attribute__((ext_vector_type(4))) _Float16 f16x4;
typedef __attribute__((ext_vector_type(4))) float f32x4;

__device__ __forceinline__ void g2l16(const void* g, void* l) {
  __builtin_amdgcn_global_load_lds(
      (const __attribute__((address_space(1))) uint32_t*)g,
      (__attribute__((address_space(3))) uint32_t*)l, 16, 0, 0);
}

// ---------------- fused weight transpose + fp32->f16 convert (all 6 weights) ----------------
__global__ __launch_bounds__(256)
void wconv_all_kernel(const float* __restrict__ Wq, const float* __restrict__ Wk,
                      const float* __restrict__ Wv, const float* __restrict__ Wp,
                      const float* __restrict__ Wfc, const float* __restrict__ Wmp,
                      f16* __restrict__ Dq, f16* __restrict__ Dk, f16* __restrict__ Dv,
                      f16* __restrict__ Dp, f16* __restrict__ Dfc, f16* __restrict__ Dmp)
{
  __shared__ float tile[32][33];
  int id = blockIdx.x;
  const float* W; f16* Wt; int K, N, local;
  if      (id < 1024) { W = Wq;  Wt = Dq;  K = 1024; N = 1024; local = id; }
  else if (id < 2048) { W = Wk;  Wt = Dk;  K = 1024; N = 1024; local = id - 1024; }
  else if (id < 3072) { W = Wv;  Wt = Dv;  K = 1024; N = 1024; local = id - 2048; }
  else if (id < 4096) { W = Wp;  Wt = Dp;  K = 1024; N = 1024; local = id - 3072; }
  else if (id < 8192) { W = Wfc; Wt = Dfc; K = 1024; N = 4096; local = id - 4096; }
  else                { W = Wmp; Wt = Dmp; K = 4096; N = 1024; local = id - 8192; }
  int ntx = N >> 5;
  int n0 = (local % ntx) * 32, k0 = (local / ntx) * 32;
  int tx = threadIdx.x & 31, ty = threadIdx.x >> 5;
#pragma unroll
  for (int i = 0; i < 4; ++i)
    tile[ty + 8*i][tx] = W[(size_t)(k0 + ty + 8*i) * N + (n0 + tx)];
  __syncthreads();
#pragma unroll
  for (int i = 0; i < 4; ++i)
    Wt[(size_t)(n0 + ty + 8*i) * K + (k0 + tx)] = (f16)tile[tx][ty + 8*i];
}

// ---------------- scaled = x*lr + x0*lx ; pre = rmsnorm(scaled) ----------------
__global__ __launch_bounds__(256)
void scale_rms_kernel(const float* __restrict__ x, const float* __restrict__ x0,
                      const float* __restrict__ lamR, const float* __restrict__ lamX,
                      float* __restrict__ scaled, f16* __restrict__ pre)
{
  const int C = 1024;
  int row = blockIdx.x, tid = threadIdx.x;
  float lr = lamR[0], lx = lamX[0];
  size_t base = (size_t)row * C;
  float4 xv = ((const float4*)(x + base))[tid];
  float4 zv = ((const float4*)(x0 + base))[tid];
  float4 sv;
  sv.x = xv.x*lr + zv.x*lx;  sv.y = xv.y*lr + zv.y*lx;
  sv.z = xv.z*lr + zv.z*lx;  sv.w = xv.w*lr + zv.w*lx;
  float ss = sv.x*sv.x + sv.y*sv.y + sv.z*sv.z + sv.w*sv.w;
#pragma unroll
  for (int off = 32; off >= 1; off >>= 1) ss += __shfl_xor(ss, off);
  __shared__ float red[4];
  if ((tid & 63) == 0) red[tid >> 6] = ss;
  __syncthreads();
  float tot = red[0] + red[1] + red[2] + red[3];
  float rs = rsqrtf(tot * (1.0f / 1024.0f) + 1e-5f);
  ((float4*)(scaled + base))[tid] = sv;
  f16* p = pre + base + tid * 4;
  p[0] = (f16)(sv.x * rs); p[1] = (f16)(sv.y * rs);
  p[2] = (f16)(sv.z * rs); p[3] = (f16)(sv.w * rs);
}

// ---------------- combine_rms: scaled2 = resid+p0+p1 (f16 partials) ; pre2 = rms ----------------
__global__ __launch_bounds__(256)
void combine_rms_kernel(const float* __restrict__ resid, const f16* __restrict__ p0,
                        const f16* __restrict__ p1, float* __restrict__ scaled2,
                        f16* __restrict__ pre2)
{
  const int C = 1024;
  int row = blockIdx.x, tid = threadIdx.x;
  size_t base = (size_t)row * C;
  float4 rv = ((const float4*)(resid + base))[tid];
  f16x4 av = ((const f16x4*)(p0 + base))[tid];
  f16x4 bv = ((const f16x4*)(p1 + base))[tid];
  float4 sv;
  sv.x = rv.x + (float)av[0] + (float)bv[0];
  sv.y = rv.y + (float)av[1] + (float)bv[1];
  sv.z = rv.z + (float)av[2] + (float)bv[2];
  sv.w = rv.w + (float)av[3] + (float)bv[3];
  float ss = sv.x*sv.x + sv.y*sv.y + sv.z*sv.z + sv.w*sv.w;
#pragma unroll
  for (int off = 32; off >= 1; off >>= 1) ss += __shfl_xor(ss, off);
  __shared__ float red[4];
  if ((tid & 63) == 0) red[tid >> 6] = ss;
  __syncthreads();
  float tot = red[0] + red[1] + red[2] + red[3];
  float rs = rsqrtf(tot * (1.0f / 1024.0f) + 1e-5f);
  ((float4*)(scaled2 + base))[tid] = sv;
  f16* p = pre2 + base + tid * 4;
  p[0] = (f16)(sv.x * rs); p[1] = (f16)(sv.y * rs);
  p[2] = (f16)(sv.z * rs); p[3] = (f16)(sv.w * rs);
}

// ---------------- combine_out: out = resid + sum of 4 f16 partials ----------------
__global__ __launch_bounds__(256)
void combine_out4_kernel(const float* __restrict__ resid, const f16* __restrict__ parts,
                         size_t pstride, float* __restrict__ out)
{
  size_t i = (size_t)blockIdx.x * 256 + threadIdx.x;
  float4 rv = ((const float4*)resid)[i];
  float4 sv = rv;
#pragma unroll
  for (int z = 0; z < 4; ++z) {
    f16x4 av = ((const f16x4*)(parts + z * pstride))[i];
    sv.x += (float)av[0]; sv.y += (float)av[1];
    sv.z += (float)av[2]; sv.w += (float)av[3];
  }
  ((float4*)out)[i] = sv;
}

// ---------------- fused RoPE + rmsnorm on q and k, (B*T, H, 64) f16 ----------------
__global__ __launch_bounds__(256)
void rope_rms_kernel(f16* __restrict__ Xq, f16* __restrict__ Xk,
                     const float* __restrict__ cs, const float* __restrict__ sn)
{
  const int MH = 4096 * 16;
  int ridx = blockIdx.x * 4 + (threadIdx.x >> 6);  // over 2*B*T*H
  f16* X = (ridx < MH) ? Xq : Xk;
  if (ridx >= MH) ridx -= MH;
  int lane = threadIdx.x & 63;
  int h = ridx & 15;
  int bt = ridx >> 4;
  int t = bt & 2047;
  size_t base = (size_t)bt * 1024 + h * 64;
  float xv = (float)X[base + lane];
  float other = __shfl_xor(xv, 32);
  float rot = (lane < 32) ? -other : other;
  float c = cs[t * 64 + lane], s = sn[t * 64 + lane];
  float y = xv * c + rot * s;
  float ss = y * y;
#pragma unroll
  for (int off = 32; off >= 1; off >>= 1) ss += __shfl_xor(ss, off);
  float r = rsqrtf(ss * (1.0f / 64.0f) + 1e-5f);
  X[base + lane] = (f16)(y * r);
}

// ---------------- legacy 128x128 GEMM (kept for proj, small N) ----------------
template<int EPI>
__global__ __launch_bounds__(256)
void gemm_kernel(const f16* __restrict__ A, const f16* __restrict__ Bt,
                 void* __restrict__ out, int M, int N, int K, int nb, int zb)
{
  __shared__ __align__(16) f16 smem[4 * 128 * 32];   // As0|As1|Bs0|Bs1
  const int tid = threadIdx.x;
  const int wave = tid >> 6, lane = tid & 63;
  const int col = lane & 15, quad = lane >> 4;
  const int id = blockIdx.x;
  const int xcd = id & 7, s = id >> 3;
  const int n_i = s % nb;
  const int p = s / nb;
  const int mpx = (M >> 7) >> 3;
  const int zz = p / mpx;
  const int m_i = xcd * mpx + (p % mpx);
  const int m0 = m_i * 128, n0 = n_i * 128;
  const int wm = (wave >> 1) * 64, wn = (wave & 1) * 64;
  const int Ksub = K / zb;
  const int kBeg = zz * Ksub;
  const int nIter = Ksub >> 5;
  f32x4 acc[4][4] = {};

  const size_t rowb = (size_t)K * 2;
  const char* Agp = (const char*)A  + (size_t)m0 * rowb;
  const char* Bgp = (const char*)Bt + (size_t)n0 * rowb;

  const int r_st = (tid >> 2);
  const int cb_st = (tid & 3) << 4;
  const int lb0 = (wave * 64) << 4;
  const int lb1 = (256 + wave * 64) << 4;

#define STAGE(buf, k0)                                                           \
  {                                                                              \
    const size_t koff = (size_t)(k0) * 2;                                        \
    g2l16(Agp + (size_t)r_st * rowb + koff + cb_st,                              \
          (char*)smem + (buf) * 8192 + lb0);                                     \
    g2l16(Agp + (size_t)(r_st + 64) * rowb + koff + cb_st,                       \
          (char*)smem + (buf) * 8192 + lb1);                                     \
    g2l16(Bgp + (size_t)r_st * rowb + koff + cb_st,                              \
          (char*)smem + 16384 + (buf) * 8192 + lb0);                             \
    g2l16(Bgp + (size_t)(r_st + 64) * rowb + koff + cb_st,                       \
          (char*)smem + 16384 + (buf) * 8192 + lb1);                             \
  }

  STAGE(0, kBeg)
  for (int kt = 0; kt < nIter; ++kt) {
    __syncthreads();
    if (kt + 1 < nIter) STAGE((kt + 1) & 1, kBeg + (kt + 1) * 32)
    const f16* As = smem + (kt & 1) * 4096;
    const f16* Bs = smem + 8192 + (kt & 1) * 4096;
    f16x8 af[4], bf[4];
#pragma unroll
    for (int t = 0; t < 4; ++t)
      af[t] = *(const f16x8*)(As + (wm + t*16 + col) * 32 + quad * 8);
#pragma unroll
    for (int t = 0; t < 4; ++t)
      bf[t] = *(const f16x8*)(Bs + (wn + t*16 + col) * 32 + quad * 8);
#pragma unroll
    for (int mt = 0; mt < 4; ++mt)
#pragma unroll
      for (int nt = 0; nt < 4; ++nt)
        acc[mt][nt] = __builtin_amdgcn_mfma_f32_16x16x32_f16(af[mt], bf[nt], acc[mt][nt], 0, 0, 0);
  }
#undef STAGE
  f16* ep = smem + wave * 1024;
  f16* outz = (EPI == 4) ? ((f16*)out + (size_t)zz * M * N) : (f16*)out;
#pragma unroll
  for (int mt = 0; mt < 4; ++mt) {
#pragma unroll
    for (int nt = 0; nt < 4; ++nt) {
#pragma unroll
      for (int r = 0; r < 4; ++r) {
        float v = acc[mt][nt][r];
        if (EPI == 1) { float tv = v > 0.0f ? v : 0.0f; v = tv * tv; }
        ep[(quad * 4 + r) * 64 + ((nt ^ quad) * 16 + col)] = (f16)v;
      }
    }
#pragma unroll
    for (int j = 0; j < 2; ++j) {
      int e = j * 64 + lane;
      int row = e >> 3, rb = e & 7;
      int phys16 = (((rb >> 1) ^ (row >> 2)) << 1) + (rb & 1);
      f16x8 vv = *(const f16x8*)(ep + row * 64 + phys16 * 8);
      int grow = m0 + wm + mt * 16 + row;
      int gcol = n0 + wn + rb * 8;
      *(f16x8*)(outz + (size_t)grow * N + gcol) = vv;
    }
  }
}

// ======================= 256x256 8-wave counted-vmcnt GEMM =======================
__device__ __forceinline__ void stage256(const char* Agp, const char* Bgp, size_t rowb,
                                         char* lds, int st_r, size_t koff, int tid)
{
#pragma unroll
  for (int j = 0; j < 4; ++j) {
    g2l16(Agp + (size_t)(st_r + j * 64) * rowb + koff, lds + j * 8192 + tid * 16);
    g2l16(Bgp + (size_t)(st_r + j * 64) * rowb + koff, lds + 32768 + j * 8192 + tid * 16);
  }
}

template<int EPI>
__global__ __launch_bounds__(512, 2)
void gemm256_kernel(const f16* __restrict__ A, const f16* __restrict__ Bt,
                    void* __restrict__ out, int M, int N, int K, int nb, int zb)
{
  __shared__ __align__(16) f16 smem[65536];   // 128 KB
  const int tid = threadIdx.x;
  const int wave = tid >> 6, lane = tid & 63;
  const int col = lane & 15, quad = lane >> 4;
  const int id = blockIdx.x;
  const int xcd = id & 7, sb = id >> 3;
  const int n_i = sb % nb;
  const int p = sb / nb;
  const int mpx = (M >> 8) >> 3;
  const int zz = p / mpx;
  const int m_i = xcd * mpx + (p % mpx);
  const int m0 = m_i * 256, n0 = n_i * 256;
  const int wm = (wave >> 2) * 128, wn = (wave & 3) * 64;
  const int Ksub = K / zb;
  const int kBeg = zz * Ksub;
  const int ntiles = Ksub >> 6;               // always even here (16)
  f32x4 acc[8][4] = {};

  const size_t rowb = (size_t)K * 2;
  const char* Agp = (const char*)A  + (size_t)m0 * rowb;
  const char* Bgp = (const char*)Bt + (size_t)n0 * rowb;

  const int st_r = tid >> 3;                                   // 0..63 row-in-64-stripe
  const size_t st_so = (size_t)(((tid & 7) ^ ((tid >> 3) & 7)) << 4);  // swizzled src slot

  stage256(Agp, Bgp, rowb, (char*)smem,         st_r, (size_t)kBeg * 2 + st_so, tid);
  stage256(Agp, Bgp, rowb, (char*)smem + 65536, st_r, (size_t)(kBeg + 64) * 2 + st_so, tid);

  for (int t = 0; t < ntiles; ++t) {
    if (t < ntiles - 1) asm volatile("s_waitcnt vmcnt(8)" ::: "memory");
    else                asm volatile("s_waitcnt vmcnt(0)" ::: "memory");
    __builtin_amdgcn_s_barrier();
    asm volatile("" ::: "memory");

    const f16* As = smem + (t & 1) * 32768;
    const f16* Bs = As + 16384;
    f16x8 bf[4][2];
#pragma unroll
    for (int ct = 0; ct < 4; ++ct)
#pragma unroll
      for (int ks = 0; ks < 2; ++ks)
        bf[ct][ks] = *(const f16x8*)(Bs + (wn + ct*16 + col) * 64 +
                                     (((ks*4 + quad) ^ (col & 7)) << 3));
#pragma unroll
    for (int sp = 0; sp < 4; ++sp) {
      f16x8 af[2][2];
#pragma unroll
      for (int i = 0; i < 2; ++i)
#pragma unroll
        for (int ks = 0; ks < 2; ++ks)
          af[i][ks] = *(const f16x8*)(As + (wm + (sp*2 + i)*16 + col) * 64 +
                                      (((ks*4 + quad) ^ (col & 7)) << 3));
      __builtin_amdgcn_s_setprio(1);
#pragma unroll
      for (int i = 0; i < 2; ++i)
#pragma unroll
        for (int ct = 0; ct < 4; ++ct)
#pragma unroll
          for (int ks = 0; ks < 2; ++ks)
            acc[sp*2 + i][ct] = __builtin_amdgcn_mfma_f32_16x16x32_f16(
                af[i][ks], bf[ct][ks], acc[sp*2 + i][ct], 0, 0, 0);
      __builtin_amdgcn_s_setprio(0);
    }

    asm volatile("s_waitcnt lgkmcnt(0)" ::: "memory");
    __builtin_amdgcn_s_barrier();
    asm volatile("" ::: "memory");
    if (t + 2 < ntiles)
      stage256(Agp, Bgp, rowb, (char*)smem + (t & 1) * 65536, st_r,
               (size_t)(kBeg + (t + 2) * 64) * 2 + st_so, tid);
  }

  // epilogue: all LDS free (loop ended with barrier); per-wave 16x64 slab
  f16* ep = smem + wave * 1024;
  f16* outz = (EPI == 4) ? ((f16*)out + (size_t)zz * M * N) : (f16*)out;
#pragma unroll
  for (int mt = 0; mt < 8; ++mt) {
#pragma unroll
    for (int ct = 0; ct < 4; ++ct) {
#pragma unroll
      for (int r = 0; r < 4; ++r) {
        float v = acc[mt][ct][r];
        if (EPI == 1) { float tv = v > 0.0f ? v : 0.0f; v = tv * tv; }
        ep[(quad * 4 + r) * 64 + ((ct ^ quad) * 16 + col)] = (f16)v;
      }
    }
#pragma unroll
    for (int j = 0; j < 2; ++j) {
      int e = j * 64 + lane;
      int row = e >> 3, rb = e & 7;
      int phys16 = (((rb >> 1) ^ (row >> 2)) << 1) + (rb & 1);
      f16x8 vv = *(const f16x8*)(ep + row * 64 + phys16 * 8);
      int grow = m0 + wm + mt * 16 + row;
      int gcol = n0 + wn + rb * 8;
      *(f16x8*)(outz + (size_t)grow * N + gcol) = vv;
    }
  }
}

// ---------------- fused QKV GEMM on the 256x256 structure ----------------
__global__ __launch_bounds__(512, 2)
void gemm256_qkv_kernel(const f16* __restrict__ A, const f16* __restrict__ Bt,
                        f16* __restrict__ qb, f16* __restrict__ kbuf, f16* __restrict__ vtg)
{
  const int K = 1024, nb = 12, ntiles = 16;
  __shared__ __align__(16) f16 smem[65536];
  const int tid = threadIdx.x;
  const int wave = tid >> 6, lane = tid & 63;
  const int col = lane & 15, quad = lane >> 4;
  const int id = blockIdx.x;
  const int xcd = id & 7, sb = id >> 3;
  const int n_i = sb % nb;
  const int m_i = xcd * 2 + (sb / nb);
  const int m0 = m_i * 256, n0 = n_i * 256;
  const int wm = (wave >> 2) * 128, wn = (wave & 3) * 64;
  f32x4 acc[8][4] = {};

  const size_t rowb = (size_t)K * 2;
  const char* Agp = (const char*)A  + (size_t)m0 * rowb;
  const char* Bgp = (const char*)Bt + (size_t)n0 * rowb;

  const int st_r = tid >> 3;
  const size_t st_so = (size_t)(((tid & 7) ^ ((tid >> 3) & 7)) << 4);

  stage256(Agp, Bgp, rowb, (char*)smem,         st_r, st_so, tid);
  stage256(Agp, Bgp, rowb, (char*)smem + 65536, st_r, (size_t)64 * 2 + st_so, tid);

  for (int t = 0; t < ntiles; ++t) {
    if (t < ntiles - 1) asm volatile("s_waitcnt vmcnt(8)" ::: "memory");
    else                asm volatile("s_waitcnt vmcnt(0)" ::: "memory");
    __builtin_amdgcn_s_barrier();
    asm volatile("" ::: "memory");

    const f16* As = smem + (t & 1) * 32768;
    const f16* Bs = As + 16384;
    f16x8 bf[4][2];
#pragma unroll
    for (int ct = 0; ct < 4; ++ct)
#pragma unroll
      for (int ks = 0; ks < 2; ++ks)
        bf[ct][ks] = *(const f16x8*)(Bs + (wn + ct*16 + col) * 64 +
                                     (((ks*4 + quad) ^ (col & 7)) << 3));
#pragma unroll
    for (int sp = 0; sp < 4; ++sp) {
      f16x8 af[2][2];
#pragma unroll
      for (int i = 0; i < 2; ++i)
#pragma unroll
        for (int ks = 0; ks < 2; ++ks)
          af[i][ks] = *(const f16x8*)(As + (wm + (sp*2 + i)*16 + col) * 64 +
                                      (((ks*4 + quad) ^ (col & 7)) << 3));
      __builtin_amdgcn_s_setprio(1);
#pragma unroll
      for (int i = 0; i < 2; ++i)
#pragma unroll
        for (int ct = 0; ct < 4; ++ct)
#pragma unroll
          for (int ks = 0; ks < 2; ++ks)
            acc[sp*2 + i][ct] = __builtin_amdgcn_mfma_f32_16x16x32_f16(
                af[i][ks], bf[ct][ks], acc[sp*2 + i][ct], 0, 0, 0);
      __builtin_amdgcn_s_setprio(0);
    }

    asm volatile("s_waitcnt lgkmcnt(0)" ::: "memory");
    __builtin_amdgcn_s_barrier();
    asm volatile("" ::: "memory");
    if (t + 2 < ntiles)
      stage256(Agp, Bgp, rowb, (char*)smem + (t & 1) * 65536, st_r,
               (size_t)((t + 2) * 64) * 2 + st_so, tid);
  }

  const int cw = n0 + wn;          // wave's 64-col base in 0..3071
  const int sel = cw >> 10;        // 0: Q, 1: K, 2: V (wave-uniform)
  if (sel < 2) {
    f16* dst = (sel == 0) ? qb : kbuf;
    const int cbase = cw & 1023;
    f16* ep = smem + wave * 1024;
#pragma unroll
    for (int mt = 0; mt < 8; ++mt) {
#pragma unroll
      for (int ct = 0; ct < 4; ++ct)
#pragma unroll
        for (int r = 0; r < 4; ++r)
          ep[(quad * 4 + r) * 64 + ((ct ^ quad) * 16 + col)] = (f16)acc[mt][ct][r];
#pragma unroll
      for (int j = 0; j < 2; ++j) {
        int e = j * 64 + lane;
        int row = e >> 3, rb = e & 7;
        int phys16 = (((rb >> 1) ^ (row >> 2)) << 1) + (rb & 1);
        f16x8 vv = *(const f16x8*)(ep + row * 64 + phys16 * 8);
        int grow = m0 + wm + mt * 16 + row;
        *(f16x8*)(dst + (size_t)grow * 1024 + cbase + rb * 8) = vv;
      }
    }
  } else {
    // V: acc[mt][ct][0..3] are 4 consecutive t (rows), same output d -> direct 8B store
#pragma unroll
    for (int mt = 0; mt < 8; ++mt) {
      int t0 = m0 + wm + mt * 16 + quad * 4;
      int b = t0 >> 11, t = t0 & 2047;
#pragma unroll
      for (int ct = 0; ct < 4; ++ct) {
        int dd = (cw & 1023) + ct * 16 + col;   // 0..1023 -> h = dd>>6, d = dd&63
        int hh = dd >> 6, d = dd & 63;
        f16x4 vv;
#pragma unroll
        for (int r = 0; r < 4; ++r) vv[r] = (f16)acc[mt][ct][r];
        *(f16x4*)(vtg + ((size_t)((b * 16 + hh) * 64 + d)) * 2048 + t) = vv;
      }
    }
  }
}

// ---------------- causal flash attention, hd=64, paired q-tiles, 8 waves ----------------
// Pair q-tile p with q-tile 31-p: every block does exactly 33 K-tile compute units.
// Waves 0-3 own the high tile (bound 31-p), waves 4-7 the low tile (bound p);
// one shared K/V dbuf staging stream. 512 uniform blocks -> 2/CU, no tail.
__global__ __launch_bounds__(512)
void attn_kernel(const f16* __restrict__ Q, const f16* __restrict__ Kc,
                 const f16* __restrict__ Vt, f16* __restrict__ O)
{
  const int T = 2048, C = 1024;
  __shared__ __align__(16) f16 Ks[2][64 * 64];
  __shared__ __align__(16) f16 Vs[2][64 * 64];
  __shared__ __align__(16) f16 Ps[8][16 * 64];
  const int tid = threadIdx.x, wave = tid >> 6, lane = tid & 63;
  const int col = lane & 15, quad = lane >> 4;
  const int bh = blockIdx.x, b = bh >> 4, h = bh & 15;
  const int pr = blockIdx.y;                  // 0..15
  const int grp = wave >> 2;                  // 0: hi tile, 1: lo tile
  const int w4 = wave & 3;
  const int hiB = 31 - pr;
  const int myB = grp ? pr : hiB;             // causal bound (inclusive), == q-tile idx
  const int q0 = myB * 64;

  const f16* qb = Q  + ((size_t)b * T) * C + h * 64;
  const f16* kb = Kc + ((size_t)b * T) * C + h * 64;
  const f16* vb = Vt + ((size_t)bh * 64) * T;

  f16x8 aq[2];
#pragma unroll
  for (int ks = 0; ks < 2; ++ks)
    aq[ks] = *(const f16x8*)(qb + (size_t)(q0 + w4*16 + col) * C + ks*32 + quad*8);

  f32x4 o_acc[4];
#pragma unroll
  for (int dt = 0; dt < 4; ++dt) o_acc[dt] = (f32x4){0.f,0.f,0.f,0.f};
  float l_part[4] = {0.f, 0.f, 0.f, 0.f};

  const int srow = lane >> 3;
  const int sblk = (lane & 7) ^ srow;
  const int r0 = wave * 8;                    // 8 rows per wave, 8 waves = 64 rows

  g2l16(kb + (size_t)(r0 + srow) * C + sblk * 8, (char*)Ks[0] + r0 * 128);
  g2l16(vb + (size_t)(r0 + srow) * T + sblk * 8, (char*)Vs[0] + r0 * 128);

  int cur = 0;
  for (int kt = 0; kt <= hiB; ++kt) {
    __syncthreads();

    if (kt < hiB) {
      const int ks1 = (kt + 1) * 64;
      g2l16(kb + (size_t)(ks1 + r0 + srow) * C + sblk * 8, (char*)Ks[cur ^ 1] + r0 * 128);
      g2l16(vb + (size_t)(r0 + srow) * T + ks1 + sblk * 8, (char*)Vs[cur ^ 1] + r0 * 128);
    }

    if (kt <= myB) {
      f32x4 s[4];
#pragma unroll
      for (int nt = 0; nt < 4; ++nt) s[nt] = (f32x4){0.f,0.f,0.f,0.f};
#pragma unroll
      for (int ks = 0; ks < 2; ++ks) {
#pragma unroll
        for (int nt = 0; nt < 4; ++nt) {
          int key = nt * 16 + col;
          f16x8 bk = *(const f16x8*)(Ks[cur] + key * 64 + (((ks*4 + quad) ^ (key & 7)) * 8));
          s[nt] = __builtin_amdgcn_mfma_f32_16x16x32_f16(aq[ks], bk, s[nt], 0, 0, 0);
        }
      }

      const bool masked = (kt == myB);
#pragma unroll
      for (int r = 0; r < 4; ++r) {
        const int qloc = quad * 4 + r;
        float p[4];
#pragma unroll
        for (int nt = 0; nt < 4; ++nt) {
          float pv = __expf(s[nt][r] * 0.125f);
          if (masked && (nt * 16 + col > w4 * 16 + qloc)) pv = 0.0f;
          p[nt] = pv;
        }
        l_part[r] += (p[0] + p[1]) + (p[2] + p[3]);
#pragma unroll
        for (int nt = 0; nt < 4; ++nt) {
          int kblk = nt * 2 + (col >> 3);
          Ps[wave][qloc * 64 + ((kblk ^ (qloc & 7)) * 8) + (col & 7)] = (f16)p[nt];
        }
      }

#pragma unroll
      for (int ks = 0; ks < 2; ++ks) {
        f16x8 ap = *(const f16x8*)(&Ps[wave][0] + col * 64 + (((ks*4 + quad) ^ (col & 7)) * 8));
#pragma unroll
        for (int dt = 0; dt < 4; ++dt) {
          int d = dt * 16 + col;
          f16x8 bv = *(const f16x8*)(Vs[cur] + d * 64 + (((ks*4 + quad) ^ (d & 7)) * 8));
          o_acc[dt] = __builtin_amdgcn_mfma_f32_16x16x32_f16(ap, bv, o_acc[dt], 0, 0, 0);
        }
      }
    }
    cur ^= 1;
  }

#pragma unroll
  for (int r = 0; r < 4; ++r) {
#pragma unroll
    for (int off = 8; off >= 1; off >>= 1)
      l_part[r] += __shfl_xor(l_part[r], off, 16);
  }
#pragma unroll
  for (int dt = 0; dt < 4; ++dt) {
#pragma unroll
    for (int r = 0; r < 4; ++r) {
      int qr = q0 + w4 * 16 + quad * 4 + r;
      float v = o_acc[dt][r] / l_part[r];
      O[((size_t)b * T + qr) * C + h * 64 + dt * 16 + col] = (f16)v;
    }
  }
}

// ---------------- orchestration ----------------
extern "C" void kernel_launch(void* const* d_in, const int* in_sizes, int n_in,
                              void* d_out, int out_size, void* d_ws, size_t ws_size,
                              hipStream_t stream)
{
  const float* x    = (const float*)d_in[0];
  const float* x0   = (const float*)d_in[1];
  const float* lamR = (const float*)d_in[2];
  const float* lamX = (const float*)d_in[3];
  const float* cs   = (const float*)d_in[4];
  const float* sn   = (const float*)d_in[5];
  const float* Wq   = (const float*)d_in[6];
  const float* Wk   = (const float*)d_in[7];
  const float* Wv   = (const float*)d_in[8];
  const float* Wp   = (const float*)d_in[9];
  const float* Wfc  = (const float*)d_in[10];
  const float* Wmp  = (const float*)d_in[11];
  float* out = (float*)d_out;

  const int B = 2, T = 2048, C = 1024, H = 16;
  const int M = B * T;  // 4096
  const size_t MB = 1ull << 20;
  char* ws = (char*)d_ws;
  f16*   Wqkv_t = (f16*)(ws + 0 * MB);     // 6 MB
  f16*   Wp_t   = (f16*)(ws + 6 * MB);     // 2 MB
  f16*   Wfc_t  = (f16*)(ws + 8 * MB);     // 8 MB
  f16*   Wmp_t  = (f16*)(ws + 16 * MB);    // 8 MB
  float* scaled  = (float*)(ws + 24 * MB); // 16 MB fp32 [later: mlp partials z0,z1]
  f16*   pre     = (f16*)(ws + 40 * MB);   // 8 MB       [later: attnOut -> mlp partial z2]
  f16*   qb      = (f16*)(ws + 48 * MB);   // 8 MB       [later: pre2 -> mlp partial z3]
  f16*   kbuf    = (f16*)(ws + 56 * MB);   // 8 MB
  f16*   vtg     = (f16*)(ws + 64 * MB);   // 8 MB V^T
  float* scaled2 = (float*)(ws + 72 * MB); // 16 MB fp32
  f16*   hbuf    = (f16*)(ws + 88 * MB);   // 32 MB      [first: proj f16 partials 2x8MB]
  f16*   attnOut = pre;
  f16*   pre2    = qb;
  f16*   projP   = (f16*)(ws + 88 * MB);   // 2 x 8 MB f16 (before hbuf written)
  f16*   mlpP    = (f16*)(ws + 24 * MB);   // 4 x 8 MB f16 (scaled/pre/qb all dead)

  dim3 tb(256);
  dim3 tb5(512);
  wconv_all_kernel<<<dim3(12288), tb, 0, stream>>>(
      Wq, Wk, Wv, Wp, Wfc, Wmp,
      Wqkv_t, Wqkv_t + 1024*1024, Wqkv_t + 2048*1024, Wp_t, Wfc_t, Wmp_t);

  scale_rms_kernel<<<M, tb, 0, stream>>>(x, x0, lamR, lamX, scaled, pre);

  // fused QKV GEMM: 256^2 tiles, 192 blocks, counted-vmcnt pipeline
  gemm256_qkv_kernel<<<dim3(192), tb5, 0, stream>>>(pre, Wqkv_t, qb, kbuf, vtg);

  rope_rms_kernel<<<(M * H) / 2, tb, 0, stream>>>(qb, kbuf, cs, sn);

  // paired-causal attention: (bh, pair) grid, 512 uniform blocks, 8 waves
  attn_kernel<<<dim3(B * H, 16), tb5, 0, stream>>>(qb, kbuf, vtg, attnOut);

  // proj GEMM split-K=2 (512 blocks, legacy 128^2) -> f16 partials ; combine + rms
  gemm_kernel<4><<<dim3(8 * 32 * 2), tb, 0, stream>>>(attnOut, Wp_t, projP, M, C, C, 8, 2);
  combine_rms_kernel<<<M, tb, 0, stream>>>(scaled, projP, projP + (size_t)M*C, scaled2, pre2);

  // fc GEMM + relu^2: 256^2 tiles, 256 blocks
  gemm256_kernel<1><<<dim3(256), tb5, 0, stream>>>(pre2, Wfc_t, hbuf, M, 4*C, C, 16, 1);

  // mlp proj split-K=4: 256^2 tiles, 256 blocks -> f16 partials ; combine into out
  gemm256_kernel<4><<<dim3(256), tb5, 0, stream>>>(hbuf, Wmp_t, mlpP, M, C, 4*C, 4, 4);
  combine_out4_kernel<<<(M*C)/1024, tb, 0, stream>>>(scaled2, mlpP, (size_t)M*C, out);
}